// Round 1
// baseline (461.240 us; speedup 1.0000x reference)
//
#include <hip/hip_runtime.h>

#define Nn   50000
#define Ee   800000
#define IND  128
#define HIDD 64
#define OUTD 32

// ---- edge_index dtype detection (int64 vs int32) ----
// If int64: entries are (lo, hi=0) word pairs since 0 <= idx < 50000.
// OR the high words of the first 1000 entries; zero => int64.
__global__ void k_detect(const unsigned int* __restrict__ p, int* __restrict__ flag) {
    __shared__ unsigned int red[256];
    unsigned int v = 0;
    for (int i = threadIdx.x; i < 1000; i += 256) v |= p[2 * i + 1];
    red[threadIdx.x] = v;
    __syncthreads();
    for (int s = 128; s > 0; s >>= 1) {
        if (threadIdx.x < s) red[threadIdx.x] |= red[threadIdx.x + s];
        __syncthreads();
    }
    if (threadIdx.x == 0) *flag = (red[0] == 0u) ? 1 : 0;
}

__global__ void k_convert(const void* __restrict__ p, const int* __restrict__ flag,
                          int* __restrict__ out) {
    int i = blockIdx.x * 256 + threadIdx.x;
    if (i >= 2 * Ee) return;
    int v;
    if (*flag) v = (int)((const long long*)p)[i];
    else       v = ((const int*)p)[i];
    out[i] = v;
}

// ---- degree / norm ----
__global__ void k_deg_init(float* __restrict__ deg) {
    int i = blockIdx.x * 256 + threadIdx.x;
    if (i < Nn) deg[i] = 1.0f;  // self-loop
}

__global__ void k_deg_count(const int* __restrict__ idx, float* __restrict__ deg) {
    int e = blockIdx.x * 256 + threadIdx.x;
    if (e < Ee) atomicAdd(&deg[idx[Ee + e]], 1.0f);  // col = targets
}

__global__ void k_dis(float* __restrict__ deg) {
    int i = blockIdx.x * 256 + threadIdx.x;
    if (i < Nn) deg[i] = rsqrtf(deg[i]);  // deg >= 1 always
}

__global__ void k_norm(const int* __restrict__ idx, const float* __restrict__ dis,
                       float* __restrict__ nrm) {
    int e = blockIdx.x * 256 + threadIdx.x;
    if (e < Ee) nrm[e] = dis[idx[e]] * dis[idx[Ee + e]];
}

// ---- GEMM1: h1[N,64] = x[N,128] @ W1[128,64] ----
__global__ __launch_bounds__(256) void k_gemm1(const float* __restrict__ x,
                                               const float* __restrict__ W,
                                               float* __restrict__ h) {
    __shared__ float Ws[IND * HIDD];   // 32 KB
    __shared__ float xs[16][IND];      // 8 KB
    int t = threadIdx.x;
    for (int i = t; i < IND * HIDD; i += 256) Ws[i] = W[i];
    int row0 = blockIdx.x * 16;
    for (int i = t; i < 16 * IND; i += 256) {
        int rr = i >> 7, kk = i & 127;
        int gr = row0 + rr;
        xs[rr][kk] = (gr < Nn) ? x[gr * IND + kk] : 0.0f;
    }
    __syncthreads();
    int j = t & 63, w = t >> 6;  // wave w handles rows w*4 .. w*4+3
    float acc[4] = {0.f, 0.f, 0.f, 0.f};
    for (int k = 0; k < IND; ++k) {
        float wv = Ws[k * HIDD + j];
        #pragma unroll
        for (int rr = 0; rr < 4; ++rr) acc[rr] = fmaf(xs[w * 4 + rr][k], wv, acc[rr]);
    }
    #pragma unroll
    for (int rr = 0; rr < 4; ++rr) {
        int gr = row0 + w * 4 + rr;
        if (gr < Nn) h[gr * HIDD + j] = acc[rr];
    }
}

// agg1[n][j] = b1[j] + dis[n]^2 * h1[n][j]   (bias + self-loop term)
__global__ void k_init_agg1(const float* __restrict__ h, const float* __restrict__ dis,
                            const float* __restrict__ b, float* __restrict__ agg) {
    int i = blockIdx.x * 256 + threadIdx.x;
    if (i >= Nn * HIDD) return;
    int n = i >> 6, j = i & 63;
    float d = dis[n];
    agg[i] = b[j] + d * d * h[i];
}

// one wave per edge, lane = feature dim (64)
__global__ void k_edge1(const int* __restrict__ idx, const float* __restrict__ nrm,
                        const float* __restrict__ h, float* __restrict__ agg) {
    int e = blockIdx.x * 4 + (threadIdx.x >> 6);
    int j = threadIdx.x & 63;
    int r = idx[e], c = idx[Ee + e];
    float w = nrm[e];
    atomicAdd(&agg[c * HIDD + j], w * h[r * HIDD + j]);
}

// ---- GEMM2: h2[N,32] = relu(agg1)[N,64] @ W2[64,32] ----
__global__ __launch_bounds__(256) void k_gemm2(const float* __restrict__ a,
                                               const float* __restrict__ W,
                                               float* __restrict__ h2) {
    __shared__ float Ws[HIDD * OUTD];  // 8 KB
    __shared__ float xs[16][HIDD];     // 4 KB
    int t = threadIdx.x;
    for (int i = t; i < HIDD * OUTD; i += 256) Ws[i] = W[i];
    int row0 = blockIdx.x * 16;
    for (int i = t; i < 16 * HIDD; i += 256) {
        int rr = i >> 6, kk = i & 63;
        int gr = row0 + rr;
        xs[rr][kk] = (gr < Nn) ? fmaxf(a[gr * HIDD + kk], 0.0f) : 0.0f;  // fused ReLU
    }
    __syncthreads();
    int j = t & 31, g = t >> 5;  // group g handles rows g*2, g*2+1
    float acc[2] = {0.f, 0.f};
    for (int k = 0; k < HIDD; ++k) {
        float wv = Ws[k * OUTD + j];
        acc[0] = fmaf(xs[g * 2 + 0][k], wv, acc[0]);
        acc[1] = fmaf(xs[g * 2 + 1][k], wv, acc[1]);
    }
    #pragma unroll
    for (int rr = 0; rr < 2; ++rr) {
        int gr = row0 + g * 2 + rr;
        if (gr < Nn) h2[gr * OUTD + j] = acc[rr];
    }
}

__global__ void k_init_out(const float* __restrict__ h2, const float* __restrict__ dis,
                           const float* __restrict__ b, float* __restrict__ out) {
    int i = blockIdx.x * 256 + threadIdx.x;
    if (i >= Nn * OUTD) return;
    int n = i >> 5, j = i & 31;
    float d = dis[n];
    out[i] = b[j] + d * d * h2[i];
}

// half-wave per edge, lane = feature dim (32)
__global__ void k_edge2(const int* __restrict__ idx, const float* __restrict__ nrm,
                        const float* __restrict__ h2, float* __restrict__ out) {
    int e = blockIdx.x * 8 + (threadIdx.x >> 5);
    int j = threadIdx.x & 31;
    int r = idx[e], c = idx[Ee + e];
    float w = nrm[e];
    atomicAdd(&out[c * OUTD + j], w * h2[r * OUTD + j]);
}

extern "C" void kernel_launch(void* const* d_in, const int* in_sizes, int n_in,
                              void* d_out, int out_size, void* d_ws, size_t ws_size,
                              hipStream_t stream) {
    const float* x  = (const float*)d_in[0];
    const void*  ei = d_in[1];                 // int32 or int64, detected on device
    const float* W1 = (const float*)d_in[2];
    const float* b1 = (const float*)d_in[3];
    const float* W2 = (const float*)d_in[4];
    const float* b2 = (const float*)d_in[5];
    float* out = (float*)d_out;

    char* w = (char*)d_ws;
    int*   flag  = (int*)w;    w += 256;
    int*   idx32 = (int*)w;    w += (size_t)2 * Ee * 4;          // 6.4 MB
    float* dis   = (float*)w;  w += ((size_t)Nn * 4 + 255) / 256 * 256;
    float* nrm   = (float*)w;  w += (size_t)Ee * 4;              // 3.2 MB
    float* h1    = (float*)w;  w += (size_t)Nn * HIDD * 4;       // 12.8 MB
    float* agg1  = (float*)w;  w += (size_t)Nn * HIDD * 4;       // 12.8 MB
    float* h2    = (float*)w;  w += (size_t)Nn * OUTD * 4;       // 6.4 MB

    k_detect   <<<1, 256, 0, stream>>>((const unsigned int*)ei, flag);
    k_convert  <<<(2 * Ee + 255) / 256, 256, 0, stream>>>(ei, flag, idx32);
    k_deg_init <<<(Nn + 255) / 256, 256, 0, stream>>>(dis);
    k_deg_count<<<(Ee + 255) / 256, 256, 0, stream>>>(idx32, dis);
    k_dis      <<<(Nn + 255) / 256, 256, 0, stream>>>(dis);
    k_norm     <<<(Ee + 255) / 256, 256, 0, stream>>>(idx32, dis, nrm);

    k_gemm1    <<<(Nn + 15) / 16, 256, 0, stream>>>(x, W1, h1);
    k_init_agg1<<<(Nn * HIDD + 255) / 256, 256, 0, stream>>>(h1, dis, b1, agg1);
    k_edge1    <<<Ee / 4, 256, 0, stream>>>(idx32, nrm, h1, agg1);

    k_gemm2    <<<(Nn + 15) / 16, 256, 0, stream>>>(agg1, W2, h2);
    k_init_out <<<(Nn * OUTD + 255) / 256, 256, 0, stream>>>(h2, dis, b2, out);
    k_edge2    <<<Ee / 8, 256, 0, stream>>>(idx32, nrm, h2, out);
}

// Round 2
// 343.321 us; speedup vs baseline: 1.3435x; 1.3435x over previous
//
#include <hip/hip_runtime.h>

#define Nn   50000
#define Ee   800000
#define IND  128
#define HIDD 64
#define OUTD 32
#define NB1  ((Nn + 255) / 256)   // 196 scan blocks

// ---- edge_index dtype detection (int64 vs int32) ----
__global__ void k_detect(const unsigned int* __restrict__ p, int* __restrict__ flag) {
    __shared__ unsigned int red[256];
    unsigned int v = 0;
    for (int i = threadIdx.x; i < 1000; i += 256) v |= p[2 * i + 1];
    red[threadIdx.x] = v;
    __syncthreads();
    for (int s = 128; s > 0; s >>= 1) {
        if (threadIdx.x < s) red[threadIdx.x] |= red[threadIdx.x + s];
        __syncthreads();
    }
    if (threadIdx.x == 0) *flag = (red[0] == 0u) ? 1 : 0;
}

// convert to int32 and count in-degree (col half) in one pass
__global__ void k_convert_count(const void* __restrict__ p, const int* __restrict__ flag,
                                int* __restrict__ out, int* __restrict__ cnt) {
    int i = blockIdx.x * 256 + threadIdx.x;
    if (i >= 2 * Ee) return;
    int v;
    if (*flag) v = (int)((const long long*)p)[i];
    else       v = ((const int*)p)[i];
    out[i] = v;
    if (i >= Ee) atomicAdd(&cnt[v], 1);
}

__global__ void k_dis(const int* __restrict__ cnt, float* __restrict__ dis) {
    int i = blockIdx.x * 256 + threadIdx.x;
    if (i < Nn) dis[i] = rsqrtf((float)cnt[i] + 1.0f);  // +1 self-loop
}

// ---- hierarchical exclusive scan over cnt[Nn] -> rowstart ----
__global__ void k_scan1(const int* __restrict__ cnt, int* __restrict__ scanned,
                        int* __restrict__ bsum) {
    __shared__ int sh[256];
    int b = blockIdx.x, t = threadIdx.x, i = b * 256 + t;
    int v = (i < Nn) ? cnt[i] : 0;
    sh[t] = v;
    __syncthreads();
    for (int off = 1; off < 256; off <<= 1) {
        int add = (t >= off) ? sh[t - off] : 0;
        __syncthreads();
        sh[t] += add;
        __syncthreads();
    }
    if (i < Nn) scanned[i] = sh[t] - v;   // exclusive
    if (t == 255) bsum[b] = sh[255];
}

__global__ void k_scan2(int* __restrict__ bsum) {
    __shared__ int sh[256];
    int t = threadIdx.x;
    int v = (t < NB1) ? bsum[t] : 0;
    sh[t] = v;
    __syncthreads();
    for (int off = 1; off < 256; off <<= 1) {
        int add = (t >= off) ? sh[t - off] : 0;
        __syncthreads();
        sh[t] += add;
        __syncthreads();
    }
    if (t < NB1) bsum[t] = sh[t] - v;     // exclusive over block sums
}

__global__ void k_scan3(const int* __restrict__ scanned, const int* __restrict__ bsum,
                        int* __restrict__ rowstart, int* __restrict__ cursor) {
    int i = blockIdx.x * 256 + threadIdx.x;
    if (i < Nn) {
        rowstart[i] = scanned[i] + bsum[blockIdx.x];
        cursor[i] = 0;
    }
    if (i == 0) rowstart[Nn] = Ee;
}

// scatter edges into CSR slots: {src row, norm}
__global__ void k_scatter(const int* __restrict__ idx, const float* __restrict__ dis,
                          const int* __restrict__ rowstart, int* __restrict__ cursor,
                          int2* __restrict__ slots) {
    int e = blockIdx.x * 256 + threadIdx.x;
    if (e >= Ee) return;
    int r = idx[e], c = idx[Ee + e];
    int pos = rowstart[c] + atomicAdd(&cursor[c], 1);
    float nr = dis[r] * dis[c];
    slots[pos] = make_int2(r, __float_as_int(nr));
}

// ---- GEMM1: h1[N,64] = x[N,128] @ W1[128,64] ----
__global__ __launch_bounds__(256) void k_gemm1(const float* __restrict__ x,
                                               const float* __restrict__ W,
                                               float* __restrict__ h) {
    __shared__ float Ws[IND * HIDD];
    __shared__ float xs[16][IND];
    int t = threadIdx.x;
    for (int i = t; i < IND * HIDD; i += 256) Ws[i] = W[i];
    int row0 = blockIdx.x * 16;
    for (int i = t; i < 16 * IND; i += 256) {
        int rr = i >> 7, kk = i & 127;
        int gr = row0 + rr;
        xs[rr][kk] = (gr < Nn) ? x[gr * IND + kk] : 0.0f;
    }
    __syncthreads();
    int j = t & 63, w = t >> 6;
    float acc[4] = {0.f, 0.f, 0.f, 0.f};
    for (int k = 0; k < IND; ++k) {
        float wv = Ws[k * HIDD + j];
        #pragma unroll
        for (int rr = 0; rr < 4; ++rr) acc[rr] = fmaf(xs[w * 4 + rr][k], wv, acc[rr]);
    }
    #pragma unroll
    for (int rr = 0; rr < 4; ++rr) {
        int gr = row0 + w * 4 + rr;
        if (gr < Nn) h[gr * HIDD + j] = acc[rr];
    }
}

// ---- layer-1 aggregation: CSR gather, 64 lanes per node, fused bias+self+ReLU ----
__global__ void k_agg1(const int2* __restrict__ slots, const int* __restrict__ rowstart,
                       const float* __restrict__ dis, const float* __restrict__ h,
                       const float* __restrict__ b, float* __restrict__ agg) {
    int n = blockIdx.x * 4 + (threadIdx.x >> 6);
    int j = threadIdx.x & 63;
    if (n >= Nn) return;
    int s = rowstart[n], e = rowstart[n + 1];
    float d = dis[n];
    float acc = b[j] + d * d * h[n * HIDD + j];
    for (int p = s; p < e; ++p) {
        int2 ed = slots[p];  // wave-uniform address -> broadcast
        acc = fmaf(__int_as_float(ed.y), h[ed.x * HIDD + j], acc);
    }
    agg[n * HIDD + j] = fmaxf(acc, 0.0f);  // fused ReLU
}

// ---- GEMM2: h2[N,32] = agg1[N,64] @ W2[64,32] ----
__global__ __launch_bounds__(256) void k_gemm2(const float* __restrict__ a,
                                               const float* __restrict__ W,
                                               float* __restrict__ h2) {
    __shared__ float Ws[HIDD * OUTD];
    __shared__ float xs[16][HIDD];
    int t = threadIdx.x;
    for (int i = t; i < HIDD * OUTD; i += 256) Ws[i] = W[i];
    int row0 = blockIdx.x * 16;
    for (int i = t; i < 16 * HIDD; i += 256) {
        int rr = i >> 6, kk = i & 63;
        int gr = row0 + rr;
        xs[rr][kk] = (gr < Nn) ? a[gr * HIDD + kk] : 0.0f;
    }
    __syncthreads();
    int j = t & 31, g = t >> 5;
    float acc[2] = {0.f, 0.f};
    for (int k = 0; k < HIDD; ++k) {
        float wv = Ws[k * OUTD + j];
        acc[0] = fmaf(xs[g * 2 + 0][k], wv, acc[0]);
        acc[1] = fmaf(xs[g * 2 + 1][k], wv, acc[1]);
    }
    #pragma unroll
    for (int rr = 0; rr < 2; ++rr) {
        int gr = row0 + g * 2 + rr;
        if (gr < Nn) h2[gr * OUTD + j] = acc[rr];
    }
}

// ---- layer-2 aggregation: 32 lanes per node, writes final output ----
__global__ void k_agg2(const int2* __restrict__ slots, const int* __restrict__ rowstart,
                       const float* __restrict__ dis, const float* __restrict__ h2,
                       const float* __restrict__ b, float* __restrict__ out) {
    int n = blockIdx.x * 8 + (threadIdx.x >> 5);
    int j = threadIdx.x & 31;
    if (n >= Nn) return;
    int s = rowstart[n], e = rowstart[n + 1];
    float d = dis[n];
    float acc = b[j] + d * d * h2[n * OUTD + j];
    for (int p = s; p < e; ++p) {
        int2 ed = slots[p];
        acc = fmaf(__int_as_float(ed.y), h2[ed.x * OUTD + j], acc);
    }
    out[n * OUTD + j] = acc;
}

extern "C" void kernel_launch(void* const* d_in, const int* in_sizes, int n_in,
                              void* d_out, int out_size, void* d_ws, size_t ws_size,
                              hipStream_t stream) {
    const float* x  = (const float*)d_in[0];
    const void*  ei = d_in[1];
    const float* W1 = (const float*)d_in[2];
    const float* b1 = (const float*)d_in[3];
    const float* W2 = (const float*)d_in[4];
    const float* b2 = (const float*)d_in[5];
    float* out = (float*)d_out;

    char* w = (char*)d_ws;
    int*   flag     = (int*)w;   w += 256;
    int*   idx32    = (int*)w;   w += (size_t)2 * Ee * 4;        // 6.4 MB
    int*   cnt      = (int*)w;   w += (size_t)Nn * 4;            // 200 KB (reused as cursor)
    int*   scanned  = (int*)w;   w += (size_t)Nn * 4;            // 200 KB
    int*   bsum     = (int*)w;   w += (size_t)NB1 * 4 + 192;
    int*   rowstart = (int*)w;   w += (size_t)(Nn + 1) * 4 + 188;
    float* dis      = (float*)w; w += (size_t)Nn * 4;            // 200 KB
    int2*  slots    = (int2*)w;  w += (size_t)Ee * 8;            // 6.4 MB
    float* h1       = (float*)w; w += (size_t)Nn * HIDD * 4;     // 12.8 MB
    float* agg1     = (float*)w; w += (size_t)Nn * HIDD * 4;     // 12.8 MB
    float* h2       = (float*)w; w += (size_t)Nn * OUTD * 4;     // 6.4 MB

    hipMemsetAsync(cnt, 0, (size_t)Nn * 4, stream);

    k_detect       <<<1, 256, 0, stream>>>((const unsigned int*)ei, flag);
    k_convert_count<<<(2 * Ee + 255) / 256, 256, 0, stream>>>(ei, flag, idx32, cnt);
    k_dis          <<<NB1, 256, 0, stream>>>(cnt, dis);
    k_scan1        <<<NB1, 256, 0, stream>>>(cnt, scanned, bsum);
    k_scan2        <<<1, 256, 0, stream>>>(bsum);
    k_scan3        <<<NB1, 256, 0, stream>>>(scanned, bsum, rowstart, cnt);  // cnt -> cursor=0
    k_scatter      <<<(Ee + 255) / 256, 256, 0, stream>>>(idx32, dis, rowstart, cnt, slots);

    k_gemm1        <<<(Nn + 15) / 16, 256, 0, stream>>>(x, W1, h1);
    k_agg1         <<<(Nn + 3) / 4, 256, 0, stream>>>(slots, rowstart, dis, h1, b1, agg1);
    k_gemm2        <<<(Nn + 15) / 16, 256, 0, stream>>>(agg1, W2, h2);
    k_agg2         <<<(Nn + 7) / 8, 256, 0, stream>>>(slots, rowstart, dis, h2, b2, out);
}

// Round 3
// 238.108 us; speedup vs baseline: 1.9371x; 1.4419x over previous
//
#include <hip/hip_runtime.h>
#include <hip/hip_fp16.h>

#define Nn   50000
#define Ee   800000
#define IND  128
#define HIDD 64
#define OUTD 32
#define NB1  ((Nn + 255) / 256)   // 196 scan blocks

// ---- edge_index dtype detection (int64 vs int32) ----
__global__ void k_detect(const unsigned int* __restrict__ p, int* __restrict__ flag) {
    __shared__ unsigned int red[256];
    unsigned int v = 0;
    for (int i = threadIdx.x; i < 1000; i += 256) v |= p[2 * i + 1];
    red[threadIdx.x] = v;
    __syncthreads();
    for (int s = 128; s > 0; s >>= 1) {
        if (threadIdx.x < s) red[threadIdx.x] |= red[threadIdx.x + s];
        __syncthreads();
    }
    if (threadIdx.x == 0) *flag = (red[0] == 0u) ? 1 : 0;
}

// count in-degree directly from raw edge_index (col half)
__global__ void k_count(const void* __restrict__ p, const int* __restrict__ flag,
                        int* __restrict__ cnt) {
    int e = blockIdx.x * 256 + threadIdx.x;
    if (e >= Ee) return;
    int c;
    if (*flag) c = (int)((const long long*)p)[Ee + e];
    else       c = ((const int*)p)[Ee + e];
    atomicAdd(&cnt[c], 1);
}

// ---- hierarchical exclusive scan over cnt[Nn] -> rowstart; dis fused ----
__global__ void k_scan1(const int* __restrict__ cnt, int* __restrict__ scanned,
                        int* __restrict__ bsum, float* __restrict__ dis) {
    __shared__ int sh[256];
    int b = blockIdx.x, t = threadIdx.x, i = b * 256 + t;
    int v = (i < Nn) ? cnt[i] : 0;
    if (i < Nn) dis[i] = rsqrtf((float)v + 1.0f);  // +1 self-loop
    sh[t] = v;
    __syncthreads();
    for (int off = 1; off < 256; off <<= 1) {
        int add = (t >= off) ? sh[t - off] : 0;
        __syncthreads();
        sh[t] += add;
        __syncthreads();
    }
    if (i < Nn) scanned[i] = sh[t] - v;   // exclusive
    if (t == 255) bsum[b] = sh[255];
}

__global__ void k_scan2(int* __restrict__ bsum) {
    __shared__ int sh[256];
    int t = threadIdx.x;
    int v = (t < NB1) ? bsum[t] : 0;
    sh[t] = v;
    __syncthreads();
    for (int off = 1; off < 256; off <<= 1) {
        int add = (t >= off) ? sh[t - off] : 0;
        __syncthreads();
        sh[t] += add;
        __syncthreads();
    }
    if (t < NB1) bsum[t] = sh[t] - v;
}

__global__ void k_scan3(const int* __restrict__ scanned, const int* __restrict__ bsum,
                        int* __restrict__ rowstart, int* __restrict__ cursor) {
    int i = blockIdx.x * 256 + threadIdx.x;
    if (i < Nn) {
        rowstart[i] = scanned[i] + bsum[blockIdx.x];
        cursor[i] = 0;
    }
    if (i == 0) rowstart[Nn] = Ee;
}

// scatter edges into CSR slots: {src row, norm}; reads raw edge_index
__global__ void k_scatter(const void* __restrict__ p, const int* __restrict__ flag,
                          const float* __restrict__ dis, const int* __restrict__ rowstart,
                          int* __restrict__ cursor, int2* __restrict__ slots) {
    int e = blockIdx.x * 256 + threadIdx.x;
    if (e >= Ee) return;
    int r, c;
    if (*flag) { r = (int)((const long long*)p)[e]; c = (int)((const long long*)p)[Ee + e]; }
    else       { r = ((const int*)p)[e];            c = ((const int*)p)[Ee + e]; }
    int pos = rowstart[c] + atomicAdd(&cursor[c], 1);
    slots[pos] = make_int2(r, __float_as_int(dis[r] * dis[c]));
}

// ---- GEMM1: h1[N,64] = x[N,128] @ W1[128,64], fp16 output ----
__global__ __launch_bounds__(256) void k_gemm1(const float* __restrict__ x,
                                               const float* __restrict__ W,
                                               __half* __restrict__ h) {
    __shared__ float Ws[IND * HIDD];
    __shared__ float xs[16][IND];
    int t = threadIdx.x;
    for (int i = t; i < IND * HIDD; i += 256) Ws[i] = W[i];
    int row0 = blockIdx.x * 16;
    for (int i = t; i < 16 * IND; i += 256) {
        int rr = i >> 7, kk = i & 127;
        xs[rr][kk] = x[(row0 + rr) * IND + kk];
    }
    __syncthreads();
    int j = t & 63, w = t >> 6;
    float acc[4] = {0.f, 0.f, 0.f, 0.f};
    for (int k = 0; k < IND; ++k) {
        float wv = Ws[k * HIDD + j];
        #pragma unroll
        for (int rr = 0; rr < 4; ++rr) acc[rr] = fmaf(xs[w * 4 + rr][k], wv, acc[rr]);
    }
    #pragma unroll
    for (int rr = 0; rr < 4; ++rr)
        h[(row0 + w * 4 + rr) * HIDD + j] = __float2half(acc[rr]);
}

// ---- layer-1 aggregation + fused GEMM2 ----
// 8 nodes/block, 32 lanes/node (half2 over 64 features); then LDS gemm2.
__global__ __launch_bounds__(256) void k_agg1(const int2* __restrict__ slots,
                                              const int* __restrict__ rowstart,
                                              const float* __restrict__ dis,
                                              const __half2* __restrict__ h1,
                                              const float* __restrict__ b1,
                                              const float* __restrict__ W2,
                                              __half* __restrict__ h2) {
    __shared__ float sh[8][HIDD];      // relu(agg) 2 KB
    __shared__ float W2s[HIDD * OUTD]; // 8 KB
    int t = threadIdx.x;
    for (int i = t; i < HIDD * OUTD; i += 256) W2s[i] = W2[i];
    int sub = t >> 5, lane = t & 31;
    int n = blockIdx.x * 8 + sub;
    int s = rowstart[n], e = rowstart[n + 1];
    float d = dis[n];
    float2 self = __half22float2(h1[n * 32 + lane]);
    float2 acc = make_float2(b1[2 * lane]     + d * d * self.x,
                             b1[2 * lane + 1] + d * d * self.y);
    int p = s;
    for (; p + 4 <= e; p += 4) {
        int2 e0 = slots[p], e1 = slots[p + 1], e2 = slots[p + 2], e3 = slots[p + 3];
        float2 v0 = __half22float2(h1[e0.x * 32 + lane]);
        float2 v1 = __half22float2(h1[e1.x * 32 + lane]);
        float2 v2 = __half22float2(h1[e2.x * 32 + lane]);
        float2 v3 = __half22float2(h1[e3.x * 32 + lane]);
        float n0 = __int_as_float(e0.y), n1 = __int_as_float(e1.y);
        float n2 = __int_as_float(e2.y), n3 = __int_as_float(e3.y);
        acc.x = fmaf(n0, v0.x, acc.x); acc.y = fmaf(n0, v0.y, acc.y);
        acc.x = fmaf(n1, v1.x, acc.x); acc.y = fmaf(n1, v1.y, acc.y);
        acc.x = fmaf(n2, v2.x, acc.x); acc.y = fmaf(n2, v2.y, acc.y);
        acc.x = fmaf(n3, v3.x, acc.x); acc.y = fmaf(n3, v3.y, acc.y);
    }
    for (; p < e; ++p) {
        int2 ed = slots[p];
        float2 v = __half22float2(h1[ed.x * 32 + lane]);
        float nr = __int_as_float(ed.y);
        acc.x = fmaf(nr, v.x, acc.x); acc.y = fmaf(nr, v.y, acc.y);
    }
    sh[sub][2 * lane]     = fmaxf(acc.x, 0.0f);
    sh[sub][2 * lane + 1] = fmaxf(acc.y, 0.0f);
    __syncthreads();
    // gemm2: thread t -> node (t>>5), output (t&31); no bias (added in agg2)
    int jn = t >> 5, j = t & 31;
    float o = 0.0f;
    #pragma unroll
    for (int k = 0; k < HIDD; ++k) o = fmaf(sh[jn][k], W2s[k * OUTD + j], o);
    h2[(blockIdx.x * 8 + jn) * OUTD + j] = __float2half(o);
}

// ---- layer-2 aggregation: 16 nodes/block, 16 lanes/node (half2 over 32) ----
__global__ __launch_bounds__(256) void k_agg2(const int2* __restrict__ slots,
                                              const int* __restrict__ rowstart,
                                              const float* __restrict__ dis,
                                              const __half2* __restrict__ h2,
                                              const float* __restrict__ b2,
                                              float* __restrict__ out) {
    int t = threadIdx.x;
    int sub = t >> 4, lane = t & 15;
    int n = blockIdx.x * 16 + sub;
    int s = rowstart[n], e = rowstart[n + 1];
    float d = dis[n];
    float2 self = __half22float2(h2[n * 16 + lane]);
    float2 acc = make_float2(b2[2 * lane]     + d * d * self.x,
                             b2[2 * lane + 1] + d * d * self.y);
    int p = s;
    for (; p + 4 <= e; p += 4) {
        int2 e0 = slots[p], e1 = slots[p + 1], e2 = slots[p + 2], e3 = slots[p + 3];
        float2 v0 = __half22float2(h2[e0.x * 16 + lane]);
        float2 v1 = __half22float2(h2[e1.x * 16 + lane]);
        float2 v2 = __half22float2(h2[e2.x * 16 + lane]);
        float2 v3 = __half22float2(h2[e3.x * 16 + lane]);
        float n0 = __int_as_float(e0.y), n1 = __int_as_float(e1.y);
        float n2 = __int_as_float(e2.y), n3 = __int_as_float(e3.y);
        acc.x = fmaf(n0, v0.x, acc.x); acc.y = fmaf(n0, v0.y, acc.y);
        acc.x = fmaf(n1, v1.x, acc.x); acc.y = fmaf(n1, v1.y, acc.y);
        acc.x = fmaf(n2, v2.x, acc.x); acc.y = fmaf(n2, v2.y, acc.y);
        acc.x = fmaf(n3, v3.x, acc.x); acc.y = fmaf(n3, v3.y, acc.y);
    }
    for (; p < e; ++p) {
        int2 ed = slots[p];
        float2 v = __half22float2(h2[ed.x * 16 + lane]);
        float nr = __int_as_float(ed.y);
        acc.x = fmaf(nr, v.x, acc.x); acc.y = fmaf(nr, v.y, acc.y);
    }
    ((float2*)out)[n * 16 + lane] = acc;
}

extern "C" void kernel_launch(void* const* d_in, const int* in_sizes, int n_in,
                              void* d_out, int out_size, void* d_ws, size_t ws_size,
                              hipStream_t stream) {
    const float* x  = (const float*)d_in[0];
    const void*  ei = d_in[1];
    const float* W1 = (const float*)d_in[2];
    const float* b1 = (const float*)d_in[3];
    const float* W2 = (const float*)d_in[4];
    const float* b2 = (const float*)d_in[5];
    float* out = (float*)d_out;

    char* w = (char*)d_ws;
    int*    flag     = (int*)w;     w += 256;
    int*    cnt      = (int*)w;     w += (size_t)Nn * 4;          // reused as cursor
    int*    scanned  = (int*)w;     w += (size_t)Nn * 4;
    int*    bsum     = (int*)w;     w += (size_t)NB1 * 4 + 240;
    int*    rowstart = (int*)w;     w += (size_t)(Nn + 1) * 4 + 188;
    float*  dis      = (float*)w;   w += (size_t)Nn * 4;
    int2*   slots    = (int2*)w;    w += (size_t)Ee * 8;          // 6.4 MB
    __half* h1       = (__half*)w;  w += (size_t)Nn * HIDD * 2;   // 6.4 MB
    __half* h2       = (__half*)w;  w += (size_t)Nn * OUTD * 2;   // 3.2 MB

    hipMemsetAsync(cnt, 0, (size_t)Nn * 4, stream);

    k_detect <<<1, 256, 0, stream>>>((const unsigned int*)ei, flag);
    k_count  <<<(Ee + 255) / 256, 256, 0, stream>>>(ei, flag, cnt);
    k_scan1  <<<NB1, 256, 0, stream>>>(cnt, scanned, bsum, dis);
    k_scan2  <<<1, 256, 0, stream>>>(bsum);
    k_scan3  <<<NB1, 256, 0, stream>>>(scanned, bsum, rowstart, cnt);  // cnt -> cursor=0
    k_scatter<<<(Ee + 255) / 256, 256, 0, stream>>>(ei, flag, dis, rowstart, cnt, slots);

    k_gemm1  <<<Nn / 16, 256, 0, stream>>>(x, W1, h1);
    k_agg1   <<<Nn / 8, 256, 0, stream>>>(slots, rowstart, dis, (const __half2*)h1, b1, W2, h2);
    k_agg2   <<<Nn / 16, 256, 0, stream>>>(slots, rowstart, dis, (const __half2*)h2, b2, out);
}

// Round 4
// 233.619 us; speedup vs baseline: 1.9743x; 1.0192x over previous
//
#include <hip/hip_runtime.h>
#include <hip/hip_fp16.h>

#define Nn   50000
#define Ee   800000
#define IND  128
#define HIDD 64
#define OUTD 32
#define NB1  ((Nn + 255) / 256)        // 196
#define CB   ((Ee / 4 + 255) / 256)    // 782 blocks, 4 edges/thread
#define GB   (Nn / 16)                 // 3125 gemm1 blocks

// ---- init: zero cnt + edge dtype detection (block 0) ----
__global__ void k_init(const unsigned int* __restrict__ p, int* __restrict__ cnt,
                       int* __restrict__ flag) {
    __shared__ unsigned int red[256];
    int i = blockIdx.x * 256 + threadIdx.x;
    if (i < Nn) cnt[i] = 0;
    if (blockIdx.x == 0) {
        unsigned int v = 0;
        for (int k = threadIdx.x; k < 1000; k += 256) v |= p[2 * k + 1];
        red[threadIdx.x] = v;
        __syncthreads();
        for (int s = 128; s > 0; s >>= 1) {
            if (threadIdx.x < s) red[threadIdx.x] |= red[threadIdx.x + s];
            __syncthreads();
        }
        if (threadIdx.x == 0) *flag = (red[0] == 0u) ? 1 : 0;  // 1 => int64
    }
}

// ---- fused: in-degree count (blocks [0,CB)) + GEMM1 (blocks [CB,CB+GB)) ----
__global__ __launch_bounds__(256) void k_count_gemm1(const void* __restrict__ p,
        const int* __restrict__ flag, int* __restrict__ cnt,
        const float* __restrict__ x, const float* __restrict__ W,
        __half* __restrict__ h) {
    __shared__ float Ws[IND * HIDD];   // 32 KB
    __shared__ float xs[16][IND];      // 8 KB
    int t = threadIdx.x;
    if (blockIdx.x < CB) {
        int base = (blockIdx.x * 256 + t) * 4;
        bool f64 = (*flag != 0);
        #pragma unroll
        for (int q = 0; q < 4; ++q) {
            int e = base + q;
            if (e < Ee) {
                int c = f64 ? (int)((const long long*)p)[Ee + e]
                            : ((const int*)p)[Ee + e];
                atomicAdd(&cnt[c], 1);
            }
        }
        return;
    }
    int bid = blockIdx.x - CB;
    for (int i = t; i < IND * HIDD; i += 256) Ws[i] = W[i];
    int row0 = bid * 16;
    for (int i = t; i < 16 * IND; i += 256) {
        int rr = i >> 7, kk = i & 127;
        xs[rr][kk] = x[(row0 + rr) * IND + kk];
    }
    __syncthreads();
    int j = t & 63, wv = t >> 6;
    float acc[4] = {0.f, 0.f, 0.f, 0.f};
    for (int k = 0; k < IND; k += 4) {
        float w0 = Ws[k * HIDD + j],       w1 = Ws[(k + 1) * HIDD + j];
        float w2 = Ws[(k + 2) * HIDD + j], w3 = Ws[(k + 3) * HIDD + j];
        #pragma unroll
        for (int rr = 0; rr < 4; ++rr) {
            float4 xv = *(const float4*)&xs[wv * 4 + rr][k];
            acc[rr] = fmaf(xv.x, w0, acc[rr]);
            acc[rr] = fmaf(xv.y, w1, acc[rr]);
            acc[rr] = fmaf(xv.z, w2, acc[rr]);
            acc[rr] = fmaf(xv.w, w3, acc[rr]);
        }
    }
    #pragma unroll
    for (int rr = 0; rr < 4; ++rr)
        h[(row0 + wv * 4 + rr) * HIDD + j] = __float2half(acc[rr]);
}

// ---- hierarchical exclusive scan (dis fused into pass 1) ----
__global__ void k_scan1(const int* __restrict__ cnt, int* __restrict__ scanned,
                        int* __restrict__ bsum, float* __restrict__ dis) {
    __shared__ int sh[256];
    int b = blockIdx.x, t = threadIdx.x, i = b * 256 + t;
    int v = (i < Nn) ? cnt[i] : 0;
    if (i < Nn) dis[i] = rsqrtf((float)v + 1.0f);  // +1 self-loop
    sh[t] = v;
    __syncthreads();
    for (int off = 1; off < 256; off <<= 1) {
        int add = (t >= off) ? sh[t - off] : 0;
        __syncthreads();
        sh[t] += add;
        __syncthreads();
    }
    if (i < Nn) scanned[i] = sh[t] - v;
    if (t == 255) bsum[b] = sh[255];
}

__global__ void k_scan2(int* __restrict__ bsum) {
    __shared__ int sh[256];
    int t = threadIdx.x;
    int v = (t < NB1) ? bsum[t] : 0;
    sh[t] = v;
    __syncthreads();
    for (int off = 1; off < 256; off <<= 1) {
        int add = (t >= off) ? sh[t - off] : 0;
        __syncthreads();
        sh[t] += add;
        __syncthreads();
    }
    if (t < NB1) bsum[t] = sh[t] - v;
}

__global__ void k_scan3(const int* __restrict__ scanned, const int* __restrict__ bsum,
                        int* __restrict__ rowstart, int* __restrict__ cursor) {
    int i = blockIdx.x * 256 + threadIdx.x;
    if (i < Nn) {
        rowstart[i] = scanned[i] + bsum[blockIdx.x];
        cursor[i] = 0;
    }
    if (i == 0) rowstart[Nn] = Ee;
}

// ---- scatter: packed 4B slots {half(dis[row])<<16 | row}, 4 edges/thread ----
__global__ void k_scatter(const void* __restrict__ p, const int* __restrict__ flag,
                          const float* __restrict__ dis, const int* __restrict__ rowstart,
                          int* __restrict__ cursor, unsigned int* __restrict__ slots) {
    int base = (blockIdx.x * 256 + threadIdx.x) * 4;
    bool f64 = (*flag != 0);
    #pragma unroll
    for (int q = 0; q < 4; ++q) {
        int e = base + q;
        if (e >= Ee) return;
        int r, c;
        if (f64) { r = (int)((const long long*)p)[e]; c = (int)((const long long*)p)[Ee + e]; }
        else     { r = ((const int*)p)[e];            c = ((const int*)p)[Ee + e]; }
        unsigned int sl = ((unsigned int)__half_as_ushort(__float2half(dis[r])) << 16)
                        | (unsigned int)r;
        int pos = rowstart[c] + atomicAdd(&cursor[c], 1);
        slots[pos] = sl;
    }
}

// ---- layer-1 aggregation + fused GEMM2: 8 nodes/block, 32 lanes/node ----
__global__ __launch_bounds__(256) void k_agg1(const unsigned int* __restrict__ slots,
        const int* __restrict__ rowstart, const float* __restrict__ dis,
        const __half2* __restrict__ h1, const float* __restrict__ b1,
        const float* __restrict__ W2, __half* __restrict__ h2) {
    __shared__ float sh[8][HIDD];      // 2 KB
    __shared__ float W2s[HIDD * OUTD]; // 8 KB
    int t = threadIdx.x;
    for (int i = t; i < HIDD * OUTD; i += 256) W2s[i] = W2[i];
    int sub = t >> 5, lane = t & 31;
    int n = blockIdx.x * 8 + sub;
    int s = rowstart[n], e = rowstart[n + 1];
    float d = dis[n];
    float2 self = __half22float2(h1[n * 32 + lane]);
    float2 acc = make_float2(b1[2 * lane]     + d * d * self.x,
                             b1[2 * lane + 1] + d * d * self.y);
    int p = s;
    for (; p + 4 <= e; p += 4) {
        unsigned int s0 = slots[p],     s1 = slots[p + 1];
        unsigned int s2 = slots[p + 2], s3 = slots[p + 3];
        float2 v0 = __half22float2(h1[(s0 & 0xFFFFu) * 32 + lane]);
        float2 v1 = __half22float2(h1[(s1 & 0xFFFFu) * 32 + lane]);
        float2 v2 = __half22float2(h1[(s2 & 0xFFFFu) * 32 + lane]);
        float2 v3 = __half22float2(h1[(s3 & 0xFFFFu) * 32 + lane]);
        float n0 = d * __half2float(__ushort_as_half((unsigned short)(s0 >> 16)));
        float n1 = d * __half2float(__ushort_as_half((unsigned short)(s1 >> 16)));
        float n2 = d * __half2float(__ushort_as_half((unsigned short)(s2 >> 16)));
        float n3 = d * __half2float(__ushort_as_half((unsigned short)(s3 >> 16)));
        acc.x = fmaf(n0, v0.x, acc.x); acc.y = fmaf(n0, v0.y, acc.y);
        acc.x = fmaf(n1, v1.x, acc.x); acc.y = fmaf(n1, v1.y, acc.y);
        acc.x = fmaf(n2, v2.x, acc.x); acc.y = fmaf(n2, v2.y, acc.y);
        acc.x = fmaf(n3, v3.x, acc.x); acc.y = fmaf(n3, v3.y, acc.y);
    }
    for (; p < e; ++p) {
        unsigned int s0 = slots[p];
        float2 v = __half22float2(h1[(s0 & 0xFFFFu) * 32 + lane]);
        float nr = d * __half2float(__ushort_as_half((unsigned short)(s0 >> 16)));
        acc.x = fmaf(nr, v.x, acc.x); acc.y = fmaf(nr, v.y, acc.y);
    }
    sh[sub][2 * lane]     = fmaxf(acc.x, 0.0f);
    sh[sub][2 * lane + 1] = fmaxf(acc.y, 0.0f);
    __syncthreads();
    int jn = t >> 5, j = t & 31;
    float o = 0.0f;
    #pragma unroll
    for (int k = 0; k < HIDD; ++k) o = fmaf(sh[jn][k], W2s[k * OUTD + j], o);
    h2[(blockIdx.x * 8 + jn) * OUTD + j] = __float2half(o);
}

// ---- layer-2 aggregation: 16 nodes/block, 16 lanes/node ----
__global__ __launch_bounds__(256) void k_agg2(const unsigned int* __restrict__ slots,
        const int* __restrict__ rowstart, const float* __restrict__ dis,
        const __half2* __restrict__ h2, const float* __restrict__ b2,
        float* __restrict__ out) {
    int t = threadIdx.x;
    int sub = t >> 4, lane = t & 15;
    int n = blockIdx.x * 16 + sub;
    int s = rowstart[n], e = rowstart[n + 1];
    float d = dis[n];
    float2 self = __half22float2(h2[n * 16 + lane]);
    float2 acc = make_float2(b2[2 * lane]     + d * d * self.x,
                             b2[2 * lane + 1] + d * d * self.y);
    int p = s;
    for (; p + 4 <= e; p += 4) {
        unsigned int s0 = slots[p],     s1 = slots[p + 1];
        unsigned int s2 = slots[p + 2], s3 = slots[p + 3];
        float2 v0 = __half22float2(h2[(s0 & 0xFFFFu) * 16 + lane]);
        float2 v1 = __half22float2(h2[(s1 & 0xFFFFu) * 16 + lane]);
        float2 v2 = __half22float2(h2[(s2 & 0xFFFFu) * 16 + lane]);
        float2 v3 = __half22float2(h2[(s3 & 0xFFFFu) * 16 + lane]);
        float n0 = d * __half2float(__ushort_as_half((unsigned short)(s0 >> 16)));
        float n1 = d * __half2float(__ushort_as_half((unsigned short)(s1 >> 16)));
        float n2 = d * __half2float(__ushort_as_half((unsigned short)(s2 >> 16)));
        float n3 = d * __half2float(__ushort_as_half((unsigned short)(s3 >> 16)));
        acc.x = fmaf(n0, v0.x, acc.x); acc.y = fmaf(n0, v0.y, acc.y);
        acc.x = fmaf(n1, v1.x, acc.x); acc.y = fmaf(n1, v1.y, acc.y);
        acc.x = fmaf(n2, v2.x, acc.x); acc.y = fmaf(n2, v2.y, acc.y);
        acc.x = fmaf(n3, v3.x, acc.x); acc.y = fmaf(n3, v3.y, acc.y);
    }
    for (; p < e; ++p) {
        unsigned int s0 = slots[p];
        float2 v = __half22float2(h2[(s0 & 0xFFFFu) * 16 + lane]);
        float nr = d * __half2float(__ushort_as_half((unsigned short)(s0 >> 16)));
        acc.x = fmaf(nr, v.x, acc.x); acc.y = fmaf(nr, v.y, acc.y);
    }
    ((float2*)out)[n * 16 + lane] = acc;
}

extern "C" void kernel_launch(void* const* d_in, const int* in_sizes, int n_in,
                              void* d_out, int out_size, void* d_ws, size_t ws_size,
                              hipStream_t stream) {
    const float* x  = (const float*)d_in[0];
    const void*  ei = d_in[1];
    const float* W1 = (const float*)d_in[2];
    const float* b1 = (const float*)d_in[3];
    const float* W2 = (const float*)d_in[4];
    const float* b2 = (const float*)d_in[5];
    float* out = (float*)d_out;

    char* w = (char*)d_ws;
    int*          flag     = (int*)w;          w += 256;
    int*          cnt      = (int*)w;          w += (size_t)Nn * 4;      // reused as cursor
    int*          scanned  = (int*)w;          w += (size_t)Nn * 4;
    int*          bsum     = (int*)w;          w += (size_t)NB1 * 4 + 240;
    int*          rowstart = (int*)w;          w += (size_t)(Nn + 1) * 4 + 188;
    float*        dis      = (float*)w;        w += (size_t)Nn * 4;
    unsigned int* slots    = (unsigned int*)w; w += (size_t)Ee * 4;      // 3.2 MB
    __half*       h1       = (__half*)w;       w += (size_t)Nn * HIDD * 2; // 6.4 MB
    __half*       h2       = (__half*)w;       w += (size_t)Nn * OUTD * 2; // 3.2 MB

    k_init       <<<NB1, 256, 0, stream>>>((const unsigned int*)ei, cnt, flag);
    k_count_gemm1<<<CB + GB, 256, 0, stream>>>(ei, flag, cnt, x, W1, h1);
    k_scan1      <<<NB1, 256, 0, stream>>>(cnt, scanned, bsum, dis);
    k_scan2      <<<1, 256, 0, stream>>>(bsum);
    k_scan3      <<<NB1, 256, 0, stream>>>(scanned, bsum, rowstart, cnt); // cnt -> cursor=0
    k_scatter    <<<CB, 256, 0, stream>>>(ei, flag, dis, rowstart, cnt, slots);
    k_agg1       <<<Nn / 8, 256, 0, stream>>>(slots, rowstart, dis, (const __half2*)h1, b1, W2, h2);
    k_agg2       <<<Nn / 16, 256, 0, stream>>>(slots, rowstart, dis, (const __half2*)h2, b2, out);
}

// Round 5
// 232.546 us; speedup vs baseline: 1.9834x; 1.0046x over previous
//
#include <hip/hip_runtime.h>
#include <hip/hip_fp16.h>

#define Nn   50000
#define Ee   800000
#define IND  128
#define HIDD 64
#define OUTD 32
#define NB1  ((Nn + 255) / 256)        // 196
#define CB   ((Ee / 4 + 255) / 256)    // 782 blocks, 4 edges/thread
#define RB   64                        // gemm1 rows per block
#define GB   ((Nn + RB - 1) / RB)      // 782 gemm1 blocks

// ---- init: zero cnt + edge dtype detection (block 0) ----
__global__ void k_init(const unsigned int* __restrict__ p, int* __restrict__ cnt,
                       int* __restrict__ flag) {
    __shared__ unsigned int red[256];
    int i = blockIdx.x * 256 + threadIdx.x;
    if (i < Nn) cnt[i] = 0;
    if (blockIdx.x == 0) {
        unsigned int v = 0;
        for (int k = threadIdx.x; k < 1000; k += 256) v |= p[2 * k + 1];
        red[threadIdx.x] = v;
        __syncthreads();
        for (int s = 128; s > 0; s >>= 1) {
            if (threadIdx.x < s) red[threadIdx.x] |= red[threadIdx.x + s];
            __syncthreads();
        }
        if (threadIdx.x == 0) *flag = (red[0] == 0u) ? 1 : 0;  // 1 => int64
    }
}

// ---- in-degree count, 4 edges/thread ----
__global__ void k_count(const void* __restrict__ p, const int* __restrict__ flag,
                        int* __restrict__ cnt) {
    int base = (blockIdx.x * 256 + threadIdx.x) * 4;
    bool f64 = (*flag != 0);
    #pragma unroll
    for (int q = 0; q < 4; ++q) {
        int e = base + q;
        if (e >= Ee) return;
        int c = f64 ? (int)((const long long*)p)[Ee + e] : ((const int*)p)[Ee + e];
        atomicAdd(&cnt[c], 1);
    }
}

// ---- hierarchical exclusive scan (dis fused into pass 1) ----
__global__ void k_scan1(const int* __restrict__ cnt, int* __restrict__ scanned,
                        int* __restrict__ bsum, float* __restrict__ dis) {
    __shared__ int sh[256];
    int b = blockIdx.x, t = threadIdx.x, i = b * 256 + t;
    int v = (i < Nn) ? cnt[i] : 0;
    if (i < Nn) dis[i] = rsqrtf((float)v + 1.0f);  // +1 self-loop
    sh[t] = v;
    __syncthreads();
    for (int off = 1; off < 256; off <<= 1) {
        int add = (t >= off) ? sh[t - off] : 0;
        __syncthreads();
        sh[t] += add;
        __syncthreads();
    }
    if (i < Nn) scanned[i] = sh[t] - v;
    if (t == 255) bsum[b] = sh[255];
}

__global__ void k_scan2(int* __restrict__ bsum) {
    __shared__ int sh[256];
    int t = threadIdx.x;
    int v = (t < NB1) ? bsum[t] : 0;
    sh[t] = v;
    __syncthreads();
    for (int off = 1; off < 256; off <<= 1) {
        int add = (t >= off) ? sh[t - off] : 0;
        __syncthreads();
        sh[t] += add;
        __syncthreads();
    }
    if (t < NB1) bsum[t] = sh[t] - v;
}

__global__ void k_scan3(const int* __restrict__ scanned, const int* __restrict__ bsum,
                        int* __restrict__ rowstart, int* __restrict__ cursor) {
    int i = blockIdx.x * 256 + threadIdx.x;
    if (i < Nn) {
        rowstart[i] = scanned[i] + bsum[blockIdx.x];
        cursor[i] = 0;
    }
    if (i == 0) rowstart[Nn] = Ee;
}

// ---- GEMM1: 4x4 register tiles, 64 rows/block, fp16 output ----
__global__ __launch_bounds__(256) void k_gemm1(const float* __restrict__ x,
                                               const float* __restrict__ W,
                                               __half* __restrict__ h) {
    __shared__ float xs[RB][IND + 4];   // pad->132: worst 2-way bank alias (free)
    __shared__ float Ws[IND * HIDD];    // 32 KB
    int t = threadIdx.x;
    int row0 = blockIdx.x * RB;
    for (int i = t; i < IND * HIDD / 4; i += 256)
        ((float4*)Ws)[i] = ((const float4*)W)[i];
    for (int i = t; i < RB * IND / 4; i += 256) {
        int rr = i >> 5, cc = (i & 31) * 4;
        int gr = row0 + rr;
        float4 v = make_float4(0.f, 0.f, 0.f, 0.f);
        if (gr < Nn) v = ((const float4*)x)[(size_t)gr * (IND / 4) + (i & 31)];
        *(float4*)&xs[rr][cc] = v;
    }
    __syncthreads();
    int jg = t & 15, rg = t >> 4;   // cols jg*4..+3, rows rg*4..+3
    float acc[4][4] = {{0.f,0.f,0.f,0.f},{0.f,0.f,0.f,0.f},
                       {0.f,0.f,0.f,0.f},{0.f,0.f,0.f,0.f}};
    for (int k = 0; k < IND; k += 4) {
        float4 xv0 = *(const float4*)&xs[rg * 4 + 0][k];
        float4 xv1 = *(const float4*)&xs[rg * 4 + 1][k];
        float4 xv2 = *(const float4*)&xs[rg * 4 + 2][k];
        float4 xv3 = *(const float4*)&xs[rg * 4 + 3][k];
        float4 w0 = *(const float4*)&Ws[(k + 0) * HIDD + jg * 4];
        float4 w1 = *(const float4*)&Ws[(k + 1) * HIDD + jg * 4];
        float4 w2 = *(const float4*)&Ws[(k + 2) * HIDD + jg * 4];
        float4 w3 = *(const float4*)&Ws[(k + 3) * HIDD + jg * 4];
        #define ROWSTEP(XV, R) \
            acc[R][0]=fmaf(XV.x,w0.x,acc[R][0]); acc[R][1]=fmaf(XV.x,w0.y,acc[R][1]); \
            acc[R][2]=fmaf(XV.x,w0.z,acc[R][2]); acc[R][3]=fmaf(XV.x,w0.w,acc[R][3]); \
            acc[R][0]=fmaf(XV.y,w1.x,acc[R][0]); acc[R][1]=fmaf(XV.y,w1.y,acc[R][1]); \
            acc[R][2]=fmaf(XV.y,w1.z,acc[R][2]); acc[R][3]=fmaf(XV.y,w1.w,acc[R][3]); \
            acc[R][0]=fmaf(XV.z,w2.x,acc[R][0]); acc[R][1]=fmaf(XV.z,w2.y,acc[R][1]); \
            acc[R][2]=fmaf(XV.z,w2.z,acc[R][2]); acc[R][3]=fmaf(XV.z,w2.w,acc[R][3]); \
            acc[R][0]=fmaf(XV.w,w3.x,acc[R][0]); acc[R][1]=fmaf(XV.w,w3.y,acc[R][1]); \
            acc[R][2]=fmaf(XV.w,w3.z,acc[R][2]); acc[R][3]=fmaf(XV.w,w3.w,acc[R][3]);
        ROWSTEP(xv0, 0) ROWSTEP(xv1, 1) ROWSTEP(xv2, 2) ROWSTEP(xv3, 3)
        #undef ROWSTEP
    }
    #pragma unroll
    for (int rr = 0; rr < 4; ++rr) {
        int gr = row0 + rg * 4 + rr;
        if (gr < Nn) {
            __half2 lo = __floats2half2_rn(acc[rr][0], acc[rr][1]);
            __half2 hi = __floats2half2_rn(acc[rr][2], acc[rr][3]);
            uint2 pk = make_uint2(*(unsigned int*)&lo, *(unsigned int*)&hi);
            *(uint2*)&h[(size_t)gr * HIDD + jg * 4] = pk;
        }
    }
}

// ---- scatter: packed 4B slots {half(dis[row])<<16 | row}, 4 edges/thread ----
__global__ void k_scatter(const void* __restrict__ p, const int* __restrict__ flag,
                          const float* __restrict__ dis, const int* __restrict__ rowstart,
                          int* __restrict__ cursor, unsigned int* __restrict__ slots) {
    int base = (blockIdx.x * 256 + threadIdx.x) * 4;
    bool f64 = (*flag != 0);
    #pragma unroll
    for (int q = 0; q < 4; ++q) {
        int e = base + q;
        if (e >= Ee) return;
        int r, c;
        if (f64) { r = (int)((const long long*)p)[e]; c = (int)((const long long*)p)[Ee + e]; }
        else     { r = ((const int*)p)[e];            c = ((const int*)p)[Ee + e]; }
        unsigned int sl = ((unsigned int)__half_as_ushort(__float2half(dis[r])) << 16)
                        | (unsigned int)r;
        int pos = rowstart[c] + atomicAdd(&cursor[c], 1);
        slots[pos] = sl;
    }
}

// ---- layer-1 aggregation + fused GEMM2: 8 nodes/block, 32 lanes/node ----
__global__ __launch_bounds__(256) void k_agg1(const unsigned int* __restrict__ slots,
        const int* __restrict__ rowstart, const float* __restrict__ dis,
        const __half2* __restrict__ h1, const float* __restrict__ b1,
        const float* __restrict__ W2, __half* __restrict__ h2) {
    __shared__ float sh[8][HIDD];      // 2 KB
    __shared__ float W2s[HIDD * OUTD]; // 8 KB
    int t = threadIdx.x;
    for (int i = t; i < HIDD * OUTD; i += 256) W2s[i] = W2[i];
    int sub = t >> 5, lane = t & 31;
    int n = blockIdx.x * 8 + sub;
    int s = rowstart[n], e = rowstart[n + 1];
    float d = dis[n];
    float2 self = __half22float2(h1[n * 32 + lane]);
    float2 acc = make_float2(b1[2 * lane]     + d * d * self.x,
                             b1[2 * lane + 1] + d * d * self.y);
    int p = s;
    for (; p + 4 <= e; p += 4) {
        unsigned int s0 = slots[p],     s1 = slots[p + 1];
        unsigned int s2 = slots[p + 2], s3 = slots[p + 3];
        float2 v0 = __half22float2(h1[(s0 & 0xFFFFu) * 32 + lane]);
        float2 v1 = __half22float2(h1[(s1 & 0xFFFFu) * 32 + lane]);
        float2 v2 = __half22float2(h1[(s2 & 0xFFFFu) * 32 + lane]);
        float2 v3 = __half22float2(h1[(s3 & 0xFFFFu) * 32 + lane]);
        float n0 = d * __half2float(__ushort_as_half((unsigned short)(s0 >> 16)));
        float n1 = d * __half2float(__ushort_as_half((unsigned short)(s1 >> 16)));
        float n2 = d * __half2float(__ushort_as_half((unsigned short)(s2 >> 16)));
        float n3 = d * __half2float(__ushort_as_half((unsigned short)(s3 >> 16)));
        acc.x = fmaf(n0, v0.x, acc.x); acc.y = fmaf(n0, v0.y, acc.y);
        acc.x = fmaf(n1, v1.x, acc.x); acc.y = fmaf(n1, v1.y, acc.y);
        acc.x = fmaf(n2, v2.x, acc.x); acc.y = fmaf(n2, v2.y, acc.y);
        acc.x = fmaf(n3, v3.x, acc.x); acc.y = fmaf(n3, v3.y, acc.y);
    }
    for (; p < e; ++p) {
        unsigned int s0 = slots[p];
        float2 v = __half22float2(h1[(s0 & 0xFFFFu) * 32 + lane]);
        float nr = d * __half2float(__ushort_as_half((unsigned short)(s0 >> 16)));
        acc.x = fmaf(nr, v.x, acc.x); acc.y = fmaf(nr, v.y, acc.y);
    }
    sh[sub][2 * lane]     = fmaxf(acc.x, 0.0f);
    sh[sub][2 * lane + 1] = fmaxf(acc.y, 0.0f);
    __syncthreads();
    int jn = t >> 5, j = t & 31;
    float o = 0.0f;
    #pragma unroll
    for (int k = 0; k < HIDD; ++k) o = fmaf(sh[jn][k], W2s[k * OUTD + j], o);
    h2[(blockIdx.x * 8 + jn) * OUTD + j] = __float2half(o);
}

// ---- layer-2 aggregation: 16 nodes/block, 16 lanes/node ----
__global__ __launch_bounds__(256) void k_agg2(const unsigned int* __restrict__ slots,
        const int* __restrict__ rowstart, const float* __restrict__ dis,
        const __half2* __restrict__ h2, const float* __restrict__ b2,
        float* __restrict__ out) {
    int t = threadIdx.x;
    int sub = t >> 4, lane = t & 15;
    int n = blockIdx.x * 16 + sub;
    int s = rowstart[n], e = rowstart[n + 1];
    float d = dis[n];
    float2 self = __half22float2(h2[n * 16 + lane]);
    float2 acc = make_float2(b2[2 * lane]     + d * d * self.x,
                             b2[2 * lane + 1] + d * d * self.y);
    int p = s;
    for (; p + 4 <= e; p += 4) {
        unsigned int s0 = slots[p],     s1 = slots[p + 1];
        unsigned int s2 = slots[p + 2], s3 = slots[p + 3];
        float2 v0 = __half22float2(h2[(s0 & 0xFFFFu) * 16 + lane]);
        float2 v1 = __half22float2(h2[(s1 & 0xFFFFu) * 16 + lane]);
        float2 v2 = __half22float2(h2[(s2 & 0xFFFFu) * 16 + lane]);
        float2 v3 = __half22float2(h2[(s3 & 0xFFFFu) * 16 + lane]);
        float n0 = d * __half2float(__ushort_as_half((unsigned short)(s0 >> 16)));
        float n1 = d * __half2float(__ushort_as_half((unsigned short)(s1 >> 16)));
        float n2 = d * __half2float(__ushort_as_half((unsigned short)(s2 >> 16)));
        float n3 = d * __half2float(__ushort_as_half((unsigned short)(s3 >> 16)));
        acc.x = fmaf(n0, v0.x, acc.x); acc.y = fmaf(n0, v0.y, acc.y);
        acc.x = fmaf(n1, v1.x, acc.x); acc.y = fmaf(n1, v1.y, acc.y);
        acc.x = fmaf(n2, v2.x, acc.x); acc.y = fmaf(n2, v2.y, acc.y);
        acc.x = fmaf(n3, v3.x, acc.x); acc.y = fmaf(n3, v3.y, acc.y);
    }
    for (; p < e; ++p) {
        unsigned int s0 = slots[p];
        float2 v = __half22float2(h2[(s0 & 0xFFFFu) * 16 + lane]);
        float nr = d * __half2float(__ushort_as_half((unsigned short)(s0 >> 16)));
        acc.x = fmaf(nr, v.x, acc.x); acc.y = fmaf(nr, v.y, acc.y);
    }
    ((float2*)out)[n * 16 + lane] = acc;
}

extern "C" void kernel_launch(void* const* d_in, const int* in_sizes, int n_in,
                              void* d_out, int out_size, void* d_ws, size_t ws_size,
                              hipStream_t stream) {
    const float* x  = (const float*)d_in[0];
    const void*  ei = d_in[1];
    const float* W1 = (const float*)d_in[2];
    const float* b1 = (const float*)d_in[3];
    const float* W2 = (const float*)d_in[4];
    const float* b2 = (const float*)d_in[5];
    float* out = (float*)d_out;

    char* w = (char*)d_ws;
    int*          flag     = (int*)w;          w += 256;
    int*          cnt      = (int*)w;          w += (size_t)Nn * 4;      // reused as cursor
    int*          scanned  = (int*)w;          w += (size_t)Nn * 4;
    int*          bsum     = (int*)w;          w += (size_t)NB1 * 4 + 240;
    int*          rowstart = (int*)w;          w += (size_t)(Nn + 1) * 4 + 188;
    float*        dis      = (float*)w;        w += (size_t)Nn * 4;
    unsigned int* slots    = (unsigned int*)w; w += (size_t)Ee * 4;        // 3.2 MB
    __half*       h1       = (__half*)w;       w += (size_t)Nn * HIDD * 2; // 6.4 MB
    __half*       h2       = (__half*)w;       w += (size_t)Nn * OUTD * 2; // 3.2 MB

    k_init   <<<NB1, 256, 0, stream>>>((const unsigned int*)ei, cnt, flag);
    k_count  <<<CB, 256, 0, stream>>>(ei, flag, cnt);
    k_scan1  <<<NB1, 256, 0, stream>>>(cnt, scanned, bsum, dis);
    k_scan2  <<<1, 256, 0, stream>>>(bsum);
    k_scan3  <<<NB1, 256, 0, stream>>>(scanned, bsum, rowstart, cnt);  // cnt -> cursor=0
    k_gemm1  <<<GB, 256, 0, stream>>>(x, W1, h1);
    k_scatter<<<CB, 256, 0, stream>>>(ei, flag, dis, rowstart, cnt, slots);
    k_agg1   <<<Nn / 8, 256, 0, stream>>>(slots, rowstart, dis, (const __half2*)h1, b1, W2, h2);
    k_agg2   <<<Nn / 16, 256, 0, stream>>>(slots, rowstart, dis, (const __half2*)h2, b2, out);
}